// Round 5
// baseline (1733.155 us; speedup 1.0000x reference)
//
#include <hip/hip_runtime.h>
#include <math.h>

typedef __bf16 bf16_t;
typedef __bf16 bfrag __attribute__((ext_vector_type(8)));
typedef float ffrag __attribute__((ext_vector_type(4)));

__device__ __forceinline__ float wave_sum(float v) {
#pragma unroll
  for (int m = 32; m >= 1; m >>= 1) v += __shfl_xor(v, m, 64);
  return v;
}
__device__ __forceinline__ float lin_(int i) { return -1.f + (2.f * (float)i) / 63.f; }
__device__ __forceinline__ float bflo(unsigned u) { return __uint_as_float(u << 16); }
__device__ __forceinline__ float bfhi(unsigned u) { return __uint_as_float(u & 0xFFFF0000u); }

// ============ setup: init state, fold LN gains into W1/Wk transposes =========
__global__ __launch_bounds__(256) void k_setup(
    const float* __restrict__ slots_p, const float* __restrict__ s_pos_p,
    const float* __restrict__ s_scale_p, const float* __restrict__ W1,
    const float* __restrict__ b1, const float* __restrict__ g_k,
    const float* __restrict__ b_k, const float* __restrict__ g_v,
    const float* __restrict__ b_v, const float* __restrict__ W_pos,
    const float* __restrict__ b_pos, const float* __restrict__ Wk,
    const float* __restrict__ Wv,
    float* __restrict__ slotsS, float* __restrict__ sposS,
    float* __restrict__ sscaleS, float* __restrict__ momentsHsum,
    bf16_t* __restrict__ W1kT, bf16_t* __restrict__ W1vT,
    bf16_t* __restrict__ WkT, bf16_t* __restrict__ WvT,
    float4* __restrict__ nckA, float* __restrict__ nckB,
    float4* __restrict__ ncvA, float* __restrict__ ncvB,
    float* __restrict__ possum, unsigned* __restrict__ ctr) {
  int t = threadIdx.x;
  for (int i = t; i < 8512; i += 256) momentsHsum[i] = 0.f;
  if (t < 8) ctr[t] = 0u;
  for (int i = t; i < 4096; i += 256) slotsS[i] = slots_p[i & 511];
  if (t < 128) {
    sposS[t] = fminf(fmaxf(s_pos_p[t & 15], -1.f), 1.f);
    sscaleS[t] = fminf(fmaxf(s_scale_p[t & 15], 0.001f), 2.f);
  }
  for (int i = t; i < 4096; i += 256) {
    int n = i >> 6, d = i & 63;
    WkT[i] = (bf16_t)Wk[d * 64 + n];
    WvT[i] = (bf16_t)Wv[d * 64 + n];
  }
  if (t < 128) {
    int n = t;
    float wxk = 0, wyk = 0, wbk = 0, uk = 0, sk = 0;
    float wxv = 0, wyv = 0, wbv = 0, uv = 0, sv = 0;
    for (int c = 0; c < 64; ++c) {
      float w = W1[c * 128 + n];
      float wk = g_k[c] * w, wv = g_v[c] * w;
      W1kT[n * 64 + c] = (bf16_t)wk;
      W1vT[n * 64 + c] = (bf16_t)wv;
      float px = W_pos[c], py = W_pos[64 + c], bp = b_pos[c];
      wxk += px * wk; wyk += py * wk; wbk += bp * wk; sk += wk; uk += b_k[c] * w;
      wxv += px * wv; wyv += py * wv; wbv += bp * wv; sv += wv; uv += b_v[c] * w;
    }
    nckA[n] = make_float4(wxk, wyk, wbk, uk + b1[n]); nckB[n] = sk;
    ncvA[n] = make_float4(wxv, wyv, wbv, uv + b1[n]); ncvB[n] = sv;
  }
  if (t < 64) {
    float px = W_pos[t], py = W_pos[64 + t], bp = b_pos[t];
    float s[9] = {px, py, bp, px * px, py * py, bp * bp, px * py, px * bp, py * bp};
#pragma unroll
    for (int i = 0; i < 9; ++i) {
      float v = wave_sum(s[i]);
      if (t == 0) possum[i] = v;
    }
  }
}

// ============ k_pre: LN(inp) -> k0/v0 -> stats + P0 = t0 @ G1 (MFMA) =========
__device__ __forceinline__ void pass_type(
    const bf16_t xs[][72], bf16_t t0s[][72],
    const bf16_t WTl[][72], const bf16_t W1l[][72],
    const float* __restrict__ bias, const float* wpxs, const float* wpys,
    const float* bpvs, float* __restrict__ statsG, bf16_t* __restrict__ P0G,
    int j0, int wv, int lq, int ln15) {
  ffrag C[4] = {{0,0,0,0},{0,0,0,0},{0,0,0,0},{0,0,0,0}};
#pragma unroll
  for (int ks = 0; ks < 2; ++ks) {
    bfrag a = *(const bfrag*)&xs[wv * 16 + ln15][ks * 32 + lq * 8];
#pragma unroll
    for (int nt = 0; nt < 4; ++nt) {
      bfrag bb = *(const bfrag*)&WTl[nt * 16 + ln15][ks * 32 + lq * 8];
      C[nt] = __builtin_amdgcn_mfma_f32_16x16x32_bf16(a, bb, C[nt], 0, 0, 0);
    }
  }
  float kv[4][4];
  float st[5][4];
#pragma unroll
  for (int i = 0; i < 5; ++i)
#pragma unroll
    for (int rg = 0; rg < 4; ++rg) st[i][rg] = 0.f;
#pragma unroll
  for (int nt = 0; nt < 4; ++nt) {
    int n = nt * 16 + ln15;
    float bn = bias[n], pxw = wpxs[n], pyw = wpys[n], bpw = bpvs[n];
#pragma unroll
    for (int rg = 0; rg < 4; ++rg) {
      float v = C[nt][rg] + bn;
      kv[nt][rg] = v;
      st[0][rg] += v; st[1][rg] += v * v; st[2][rg] += v * pxw;
      st[3][rg] += v * pyw; st[4][rg] += v * bpw;
    }
  }
#pragma unroll
  for (int i = 0; i < 5; ++i)
#pragma unroll
    for (int rg = 0; rg < 4; ++rg) {
      float v = st[i][rg];
      v += __shfl_xor(v, 1, 64); v += __shfl_xor(v, 2, 64);
      v += __shfl_xor(v, 4, 64); v += __shfl_xor(v, 8, 64);
      st[i][rg] = v;
    }
  if (ln15 == 0) {
#pragma unroll
    for (int rg = 0; rg < 4; ++rg) {
      int j = j0 + wv * 16 + lq * 4 + rg;
#pragma unroll
      for (int i = 0; i < 5; ++i) statsG[j * 5 + i] = st[i][rg];
    }
  }
#pragma unroll
  for (int nt = 0; nt < 4; ++nt)
#pragma unroll
    for (int rg = 0; rg < 4; ++rg)
      t0s[wv * 16 + lq * 4 + rg][nt * 16 + ln15] = (bf16_t)kv[nt][rg];
  ffrag D[8] = {{0,0,0,0},{0,0,0,0},{0,0,0,0},{0,0,0,0},
                {0,0,0,0},{0,0,0,0},{0,0,0,0},{0,0,0,0}};
#pragma unroll
  for (int ks = 0; ks < 2; ++ks) {
    bfrag a = *(const bfrag*)&t0s[wv * 16 + ln15][ks * 32 + lq * 8];
#pragma unroll
    for (int nt = 0; nt < 8; ++nt) {
      bfrag bb = *(const bfrag*)&W1l[nt * 16 + ln15][ks * 32 + lq * 8];
      D[nt] = __builtin_amdgcn_mfma_f32_16x16x32_bf16(a, bb, D[nt], 0, 0, 0);
    }
  }
#pragma unroll
  for (int nt = 0; nt < 8; ++nt)
#pragma unroll
    for (int rg = 0; rg < 4; ++rg)
      P0G[(size_t)(j0 + wv * 16 + lq * 4 + rg) * 128 + nt * 16 + ln15] =
          (bf16_t)D[nt][rg];
}

__global__ __launch_bounds__(256) void k_pre(
    const float* __restrict__ inp, const float* __restrict__ g_in,
    const float* __restrict__ b_in, const float* __restrict__ bk,
    const float* __restrict__ bv, const bf16_t* __restrict__ WkT,
    const bf16_t* __restrict__ WvT, const bf16_t* __restrict__ W1kT,
    const bf16_t* __restrict__ W1vT, const float* __restrict__ W_pos,
    const float* __restrict__ b_pos,
    bf16_t* __restrict__ P0k, bf16_t* __restrict__ P0v,
    float* __restrict__ statsK, float* __restrict__ statsV,
    const float* __restrict__ slotsS, const float* __restrict__ g_slots,
    const float* __restrict__ b_slots, const float* __restrict__ Wq,
    const float* __restrict__ bq, const float* __restrict__ W2,
    const float* __restrict__ b2, float* __restrict__ w2qg,
    float* __restrict__ b2qg) {
  __shared__ bf16_t xs[64][72];
  __shared__ bf16_t t0s[64][72];
  __shared__ bf16_t WkTl[64][72];
  __shared__ bf16_t WvTl[64][72];
  __shared__ bf16_t W1kl[128][72];
  __shared__ bf16_t W1vl[128][72];
  __shared__ float wpxs[64], wpys[64], bpvs[64];
  const int tid = threadIdx.x;
  const int j0 = blockIdx.x * 64;
  for (int i = tid; i < 512; i += 256) {
    int row = i >> 3, seg = i & 7;
    *(uint4*)&WkTl[row][seg * 8] = ((const uint4*)WkT)[i];
    *(uint4*)&WvTl[row][seg * 8] = ((const uint4*)WvT)[i];
  }
  for (int i = tid; i < 1024; i += 256) {
    int row = i >> 3, seg = i & 7;
    *(uint4*)&W1kl[row][seg * 8] = ((const uint4*)W1kT)[i];
    *(uint4*)&W1vl[row][seg * 8] = ((const uint4*)W1vT)[i];
  }
  if (tid < 64) { wpxs[tid] = W_pos[tid]; wpys[tid] = W_pos[64 + tid]; bpvs[tid] = b_pos[tid]; }
  {
    const int px = tid >> 2, cg = tid & 3;
    const float* rowp = inp + (size_t)(j0 + px) * 64 + cg * 16;
    float v[16];
    *(float4*)&v[0]  = ((const float4*)rowp)[0];
    *(float4*)&v[4]  = ((const float4*)rowp)[1];
    *(float4*)&v[8]  = ((const float4*)rowp)[2];
    *(float4*)&v[12] = ((const float4*)rowp)[3];
    float s = 0.f, s2 = 0.f;
#pragma unroll
    for (int i = 0; i < 16; ++i) { s += v[i]; s2 += v[i] * v[i]; }
    s += __shfl_xor(s, 1, 64); s += __shfl_xor(s, 2, 64);
    s2 += __shfl_xor(s2, 1, 64); s2 += __shfl_xor(s2, 2, 64);
    float m = s * 0.015625f;
    float r = rsqrtf(s2 * 0.015625f - m * m + 1e-5f);
    float g[16], bb[16];
    *(float4*)&g[0]  = ((const float4*)(g_in + cg * 16))[0];
    *(float4*)&g[4]  = ((const float4*)(g_in + cg * 16))[1];
    *(float4*)&g[8]  = ((const float4*)(g_in + cg * 16))[2];
    *(float4*)&g[12] = ((const float4*)(g_in + cg * 16))[3];
    *(float4*)&bb[0]  = ((const float4*)(b_in + cg * 16))[0];
    *(float4*)&bb[4]  = ((const float4*)(b_in + cg * 16))[1];
    *(float4*)&bb[8]  = ((const float4*)(b_in + cg * 16))[2];
    *(float4*)&bb[12] = ((const float4*)(b_in + cg * 16))[3];
#pragma unroll
    for (int e = 0; e < 8; ++e) {
      float x0 = (v[2 * e] - m) * r * g[2 * e] + bb[2 * e];
      float x1 = (v[2 * e + 1] - m) * r * g[2 * e + 1] + bb[2 * e + 1];
      union { unsigned u; bf16_t h[2]; } cv;
      cv.h[0] = (bf16_t)x0; cv.h[1] = (bf16_t)x1;
      *(unsigned*)&xs[px][cg * 16 + 2 * e] = cv.u;
    }
  }
  __syncthreads();
  const int wv = tid >> 6, lane = tid & 63, lq = lane >> 4, ln15 = lane & 15;
  pass_type(xs, t0s, WkTl, W1kl, bk, wpxs, wpys, bpvs, statsK, P0k, j0, wv, lq, ln15);
  pass_type(xs, t0s, WvTl, W1vl, bv, wpxs, wpys, bpvs, statsV, P0v, j0, wv, lq, ln15);
  // initial q / w2q / b2q (wave 0 of first 64 blocks)
  if (blockIdx.x < 64 && tid < 64) {
    int bs = blockIdx.x, d = tid;
    float v = slotsS[bs * 64 + d];
    float m = wave_sum(v) * 0.015625f;
    float c = v - m;
    float var = wave_sum(c * c) * 0.015625f;
    float xn = c * rsqrtf(var + 1e-5f) * g_slots[d] + b_slots[d];
    float q = bq[d];
    for (int cc = 0; cc < 64; ++cc) q = fmaf(__shfl(xn, cc, 64), Wq[cc * 64 + d], q);
    float w0 = 0.f, w1 = 0.f;
    for (int cc = 0; cc < 64; ++cc) {
      float qc = __shfl(q, cc, 64);
      w0 = fmaf(W2[d * 64 + cc], qc, w0);
      w1 = fmaf(W2[(64 + d) * 64 + cc], qc, w1);
    }
    w2qg[bs * 128 + d] = w0;
    w2qg[bs * 128 + 64 + d] = w1;
    float p = wave_sum(b2[d] * q);
    if (d == 0) b2qg[bs] = p;
  }
}

// ============ k_iter: dots -> softmax -> moments -> V-hidden sum -> finalize =
template <int LAST>
__global__ __launch_bounds__(256) void k_iter(
    const bf16_t* __restrict__ P0kg, const bf16_t* __restrict__ P0vg,
    const float* __restrict__ statsK, const float* __restrict__ statsV,
    const float4* __restrict__ nckA, const float* __restrict__ nckB,
    const float4* __restrict__ ncvA, const float* __restrict__ ncvB,
    const float* __restrict__ possum, float* __restrict__ w2qg,
    float* __restrict__ b2qg, float* __restrict__ sposS,
    float* __restrict__ sscaleS, float* __restrict__ moments,
    float* __restrict__ Hsum, float* __restrict__ outAttn,
    const float* __restrict__ W2, const float* __restrict__ b2,
    const float* __restrict__ W_ih, const float* __restrict__ b_ih,
    const float* __restrict__ W_hh, const float* __restrict__ b_hh,
    const float* __restrict__ g_pre, const float* __restrict__ b_pre,
    const float* __restrict__ Wf1, const float* __restrict__ bf1,
    const float* __restrict__ Wf2, const float* __restrict__ bf2,
    const float* __restrict__ g_slots, const float* __restrict__ b_slots,
    const float* __restrict__ Wq, const float* __restrict__ bq,
    float* __restrict__ slotsS, float* __restrict__ outSlots,
    float* __restrict__ outSpos, float* __restrict__ outSscale,
    unsigned* __restrict__ ctr) {
  __shared__ unsigned P0kl[64 * 65];
  __shared__ unsigned P0vl[64 * 65];
  __shared__ float nck12[64][12];    // per-k' row: A0(4) A1(4) ws0 ws1 pad(2)
  __shared__ float w2q16[64][16];    // per-k' row: q[n even][8s], q[n odd][8s]
  __shared__ float4 scalV[64][9];
  __shared__ float attnS[64][10];
  __shared__ float HsumT[8][128];
  __shared__ float momAcc[8][5];
  __shared__ unsigned s_done;
  // finalize scratch
  __shared__ float mom_s[5], hsum_s[128], upd[64], sprev[64], xg[192], hg[192];
  __shared__ float snew[64], xpre[64], hf[128], sfin[64], xn[64], qsh[64];
  const int tid = threadIdx.x;
  const int tile = blockIdx.x, b = blockIdx.y;
  const int jg0 = b * 4096 + tile * 64;
#pragma unroll
  for (int r = 0; r < 4; ++r) {
    int idx = tid + 256 * r;
    int row = idx >> 4, seg = idx & 15;
    uint4 v = ((const uint4*)P0kg)[(size_t)(jg0 + row) * 16 + seg];
    unsigned* dst = &P0kl[row * 65 + seg * 4];
    dst[0] = v.x; dst[1] = v.y; dst[2] = v.z; dst[3] = v.w;
    if (!LAST) {
      uint4 w = ((const uint4*)P0vg)[(size_t)(jg0 + row) * 16 + seg];
      unsigned* d2 = &P0vl[row * 65 + seg * 4];
      d2[0] = w.x; d2[1] = w.y; d2[2] = w.z; d2[3] = w.w;
    }
  }
  if (tid < 128) {
    int n = tid, k = n >> 1, h = n & 1;
    int kp = ((k & 15) << 2) | (k >> 4);
    float4 A = nckA[n];
    *(float4*)&nck12[kp][h * 4] = A;
    nck12[kp][8 + h] = nckB[n];
  }
#pragma unroll
  for (int r = 0; r < 4; ++r) {
    int idx = tid + 256 * r;
    int s = idx >> 7, n = idx & 127;
    int k = n >> 1, h = n & 1;
    int kp = ((k & 15) << 2) | (k >> 4);
    w2q16[kp][h * 8 + s] = w2qg[(b * 8 + s) * 128 + n];
  }
  if (!LAST) {
#pragma unroll
    for (int r = 0; r < 4; ++r) ((float*)HsumT)[tid + 256 * r] = 0.f;
  }
  if (tid < 40) momAcc[tid / 5][tid % 5] = 0.f;
  float4 ncv0 = {0, 0, 0, 0}, ncv1 = {0, 0, 0, 0};
  float wsv0 = 0.f, wsv1 = 0.f;
  if (!LAST) {
    int l = tid & 63;
    ncv0 = ncvA[l]; ncv1 = ncvA[l + 64];
    wsv0 = ncvB[l]; wsv1 = ncvB[l + 64];
  }
  __syncthreads();

  // ---- phase 1: dots for all 8 slots (k-range split over 4 lanes/pixel) ----
  const int px = tid >> 2, sp = tid & 3;
  const int jimg = tile * 64 + px;
  const float gx = lin_(jimg & 63), gy = lin_(jimg >> 6);
  const float Swx = possum[0], Swy = possum[1], Sbp = possum[2];
  const float Swx2 = possum[3], Swy2 = possum[4], Sbp2 = possum[5];
  const float Swxy = possum[6], Swxb = possum[7], Swyb = possum[8];
  float skA[5], svA[5];
#pragma unroll
  for (int i = 0; i < 5; ++i) {
    skA[i] = statsK[(size_t)(jg0 + px) * 5 + i];
    if (!LAST) svA[i] = statsV[(size_t)(jg0 + px) * 5 + i];
  }
  float c1a[8], c2a[8], rKa[8], mrKa[8];
#pragma unroll
  for (int s = 0; s < 8; ++s) {
    int bs = b * 8 + s;
    float spx = sposS[bs * 2], spy = sposS[bs * 2 + 1];
    float rxx = 1.f / (sscaleS[bs * 2] * 5.f);
    float ryy = 1.f / (sscaleS[bs * 2 + 1] * 5.f);
    float c1 = (gx - spx) * rxx, c2 = (gy - spy) * ryy;
    float quad = c1 * c1 * Swx2 + c2 * c2 * Swy2 + Sbp2 +
                 2.f * (c1 * c2 * Swxy + c1 * Swxb + c2 * Swyb);
    float mK = (skA[0] + c1 * Swx + c2 * Swy + Sbp) * 0.015625f;
    float e2K = (skA[1] + 2.f * (c1 * skA[2] + c2 * skA[3] + skA[4]) + quad) * 0.015625f;
    float rK = rsqrtf(e2K - mK * mK + 1e-5f);
    c1a[s] = c1; c2a[s] = c2; rKa[s] = rK; mrKa[s] = mK * rK;
    if (!LAST && (s >> 1) == sp) {
      float mV = (svA[0] + c1 * Swx + c2 * Swy + Sbp) * 0.015625f;
      float e2V = (svA[1] + 2.f * (c1 * svA[2] + c2 * svA[3] + svA[4]) + quad) * 0.015625f;
      float rV = rsqrtf(e2V - mV * mV + 1e-5f);
      scalV[px][s] = make_float4(c1, c2, rV, mV * rV);
    }
  }
  float d8[8] = {0, 0, 0, 0, 0, 0, 0, 0};
#pragma unroll 4
  for (int i = 0; i < 16; ++i) {
    int k = sp * 16 + i;
    unsigned u = P0kl[px * 65 + k];
    float p0 = bflo(u), p1 = bfhi(u);
    const int kp = (i << 2) | sp;
    const float* nr = &nck12[kp][0];
    float4 A0 = *(const float4*)nr;
    float4 A1 = *(const float4*)(nr + 4);
    float ws0 = nr[8], ws1 = nr[9];
    const float* wr = &w2q16[kp][0];
    float4 q0a = *(const float4*)wr;
    float4 q0b = *(const float4*)(wr + 4);
    float4 q1a = *(const float4*)(wr + 8);
    float4 q1b = *(const float4*)(wr + 12);
    float qq0[8] = {q0a.x, q0a.y, q0a.z, q0a.w, q0b.x, q0b.y, q0b.z, q0b.w};
    float qq1[8] = {q1a.x, q1a.y, q1a.z, q1a.w, q1b.x, q1b.y, q1b.z, q1b.w};
    float bm0 = p0 + A0.z, bm1 = p1 + A1.z;
#pragma unroll
    for (int s = 0; s < 8; ++s) {
      float z0 = bm0 + c1a[s] * A0.x + c2a[s] * A0.y;
      float h0 = fmaxf(fmaf(rKa[s], z0, fmaf(-mrKa[s], ws0, A0.w)), 0.f);
      d8[s] = fmaf(h0, qq0[s], d8[s]);
      float z1 = bm1 + c1a[s] * A1.x + c2a[s] * A1.y;
      float h1 = fmaxf(fmaf(rKa[s], z1, fmaf(-mrKa[s], ws1, A1.w)), 0.f);
      d8[s] = fmaf(h1, qq1[s], d8[s]);
    }
  }
#pragma unroll
  for (int s = 0; s < 8; ++s) {
    float v = d8[s];
    v += __shfl_xor(v, 1, 64);
    v += __shfl_xor(v, 2, 64);
    d8[s] = (v + b2qg[b * 8 + s]) * 0.125f;
  }
  float mx = d8[0];
#pragma unroll
  for (int s = 1; s < 8; ++s) mx = fmaxf(mx, d8[s]);
  float tt = 0.f;
  float e8[8];
#pragma unroll
  for (int s = 0; s < 8; ++s) { e8[s] = expf(d8[s] - mx); tt += e8[s]; }
  float inv = 1.f / tt;
#pragma unroll
  for (int s = 0; s < 8; ++s) e8[s] = e8[s] * inv + 1e-8f;
  float wa, wb;
  if (sp == 0) { wa = e8[0]; wb = e8[1]; }
  else if (sp == 1) { wa = e8[2]; wb = e8[3]; }
  else if (sp == 2) { wa = e8[4]; wb = e8[5]; }
  else { wa = e8[6]; wb = e8[7]; }
  *(float2*)&attnS[px][sp * 2] = make_float2(wa, wb);
  if (LAST) {
    outAttn[(size_t)(b * 8 + sp * 2) * 4096 + jimg] = wa;
    outAttn[(size_t)(b * 8 + sp * 2 + 1) * 4096 + jimg] = wb;
  }
  {
    float mm[10] = {wa, wa * gx, wa * gy, wa * gx * gx, wa * gy * gy,
                    wb, wb * gx, wb * gy, wb * gx * gx, wb * gy * gy};
#pragma unroll
    for (int i = 0; i < 10; ++i) {
      float v = mm[i];
      v += __shfl_xor(v, 4, 64); v += __shfl_xor(v, 8, 64);
      v += __shfl_xor(v, 16, 64); v += __shfl_xor(v, 32, 64);
      mm[i] = v;
    }
    if ((tid & 63) < 4) {
#pragma unroll
      for (int i = 0; i < 5; ++i) {
        atomicAdd(&momAcc[sp * 2][i], mm[i]);
        atomicAdd(&momAcc[sp * 2 + 1][i], mm[5 + i]);
      }
    }
  }
  __syncthreads();

  // ---- phase 2: Hsum += attn * relu(V hidden) ------------------------------
  if (!LAST) {
    const int w = tid >> 6, l = tid & 63;
    float hacc[8][2];
#pragma unroll
    for (int s = 0; s < 8; ++s) { hacc[s][0] = 0.f; hacc[s][1] = 0.f; }
    const unsigned short* P16 = (const unsigned short*)P0vl;
#pragma unroll 2
    for (int i = 0; i < 16; ++i) {
      int j = w * 16 + i;
      float pv0 = __uint_as_float((unsigned)P16[j * 130 + l] << 16);
      float pv1 = __uint_as_float((unsigned)P16[j * 130 + 64 + l] << 16);
      float bm0 = pv0 + ncv0.z, bm1 = pv1 + ncv1.z;
#pragma unroll
      for (int s = 0; s < 8; ++s) {
        float4 sc = scalV[j][s];
        float aw = attnS[j][s];
        float z0 = bm0 + sc.x * ncv0.x + sc.y * ncv0.y;
        float h0 = fmaxf(fmaf(sc.z, z0, fmaf(-sc.w, wsv0, ncv0.w)), 0.f);
        hacc[s][0] = fmaf(aw, h0, hacc[s][0]);
        float z1 = bm1 + sc.x * ncv1.x + sc.y * ncv1.y;
        float h1 = fmaxf(fmaf(sc.z, z1, fmaf(-sc.w, wsv1, ncv1.w)), 0.f);
        hacc[s][1] = fmaf(aw, h1, hacc[s][1]);
      }
    }
#pragma unroll
    for (int s = 0; s < 8; ++s) {
      atomicAdd(&HsumT[s][l], hacc[s][0]);
      atomicAdd(&HsumT[s][l + 64], hacc[s][1]);
    }
    __syncthreads();
#pragma unroll
    for (int r = 0; r < 4; ++r) {
      int i2 = tid + 256 * r;
      int s = i2 >> 7, n = i2 & 127;
      atomicAdd(&Hsum[(b * 8 + s) * 128 + n], HsumT[s][n]);
    }
  }
  if (tid < 40)
    atomicAdd(&moments[(b * 8 + tid / 5) * 5 + tid % 5], momAcc[tid / 5][tid % 5]);
  __syncthreads();   // drains all global atomics (vmcnt) for every thread

  // ---- completion counter: last block for this b runs the finalize ----------
  __threadfence();
  if (tid == 0) s_done = atomicAdd(&ctr[b], 1u);
  __syncthreads();
  if (s_done != 63) return;
  __threadfence();
  const int t = tid;
  for (int s = 0; s < 8; ++s) {
    const int bs = b * 8 + s;
    if (t < 5) mom_s[t] = atomicAdd(&moments[bs * 5 + t], 0.f);
    if (!LAST && t < 128) hsum_s[t] = atomicAdd(&Hsum[bs * 128 + t], 0.f);
    if (t < 64) sprev[t] = slotsS[bs * 64 + t];
    __syncthreads();
    const float M0 = mom_s[0], M1x = mom_s[1], M1y = mom_s[2];
    const float M2x = mom_s[3], M2y = mom_s[4];
    const float invM0 = 1.f / M0;
    const float spx2 = M1x * invM0, spy2 = M1y * invM0;
    const float M0a = M0 + 4096.f * 1e-8f;
    const float G2 = 1408.6772487f * 1e-8f;
    const float vx = (M2x + G2 - 2.f * spx2 * M1x + spx2 * spx2 * M0a) / M0a;
    const float vy = (M2y + G2 - 2.f * spy2 * M1y + spy2 * spy2 * M0a) / M0a;
    float ssx = fminf(fmaxf(sqrtf(fmaxf(vx, 0.f)), 0.001f), 2.f);
    float ssy = fminf(fmaxf(sqrtf(fmaxf(vy, 0.f)), 0.001f), 2.f);
    if (t == 0) {
      sposS[bs * 2] = spx2; sposS[bs * 2 + 1] = spy2;
      sscaleS[bs * 2] = ssx; sscaleS[bs * 2 + 1] = ssy;
      if (LAST) {
        outSpos[bs * 2] = spx2; outSpos[bs * 2 + 1] = spy2;
        outSscale[bs * 2] = ssx; outSscale[bs * 2 + 1] = ssy;
      }
    }
    if (LAST) {
      if (t < 64) outSlots[bs * 64 + t] = sprev[t];
      __syncthreads();
    } else {
      if (t < 5) moments[bs * 5 + t] = 0.f;
      if (t < 128) Hsum[bs * 128 + t] = 0.f;
      if (t < 64) {
        float a = 0.f;
#pragma unroll
        for (int k2 = 0; k2 < 128; ++k2) a += hsum_s[k2] * W2[k2 * 64 + t];
        upd[t] = a * invM0 + b2[t];
      }
      __syncthreads();
      if (t < 192) {
        float a = b_ih[t], h = b_hh[t];
#pragma unroll
        for (int d = 0; d < 64; ++d) {
          a += upd[d] * W_ih[d * 192 + t];
          h += sprev[d] * W_hh[d * 192 + t];
        }
        xg[t] = a; hg[t] = h;
      }
      __syncthreads();
      if (t < 64) {
        float r = 1.f / (1.f + expf(-(xg[t] + hg[t])));
        float z = 1.f / (1.f + expf(-(xg[64 + t] + hg[64 + t])));
        float n = tanhf(xg[128 + t] + r * hg[128 + t]);
        snew[t] = (1.f - z) * n + z * sprev[t];
      }
      __syncthreads();
      if (t < 64) {
        float v = snew[t];
        float m = wave_sum(v) * 0.015625f;
        float c = v - m;
        float var = wave_sum(c * c) * 0.015625f;
        xpre[t] = c * rsqrtf(var + 1e-5f) * g_pre[t] + b_pre[t];
      }
      __syncthreads();
      if (t < 128) {
        float a = bf1[t];
#pragma unroll
        for (int d = 0; d < 64; ++d) a += xpre[d] * Wf1[d * 128 + t];
        hf[t] = fmaxf(a, 0.f);
      }
      __syncthreads();
      if (t < 64) {
        float a = bf2[t];
#pragma unroll
        for (int k2 = 0; k2 < 128; ++k2) a += hf[k2] * Wf2[k2 * 64 + t];
        float nv = snew[t] + a;
        slotsS[bs * 64 + t] = nv;
        sfin[t] = nv;
      }
      __syncthreads();
      if (t < 64) {
        float v = sfin[t];
        float m = wave_sum(v) * 0.015625f;
        float c = v - m;
        float var = wave_sum(c * c) * 0.015625f;
        xn[t] = c * rsqrtf(var + 1e-5f) * g_slots[t] + b_slots[t];
      }
      __syncthreads();
      if (t < 64) {
        float a = bq[t];
#pragma unroll
        for (int d = 0; d < 64; ++d) a += xn[d] * Wq[d * 64 + t];
        qsh[t] = a;
      }
      __syncthreads();
      if (t < 128) {
        float a = 0.f;
#pragma unroll
        for (int d = 0; d < 64; ++d) a += W2[t * 64 + d] * qsh[d];
        w2qg[bs * 128 + t] = a;
      }
      if (t < 64) {
        float p = wave_sum(b2[t] * qsh[t]);
        if (t == 0) b2qg[bs] = p;
      }
      __syncthreads();
    }
  }
  if (tid == 0) atomicExch(&ctr[b], 0u);
}

extern "C" void kernel_launch(void* const* d_in, const int* in_sizes, int n_in,
                              void* d_out, int out_size, void* d_ws, size_t ws_size,
                              hipStream_t stream) {
  const float* const* in = (const float* const*)d_in;
  float* ws = (float*)d_ws;
  bf16_t* P0k   = (bf16_t*)(ws + 0);
  bf16_t* P0v   = (bf16_t*)(ws + 2097152);
  float* statsK = ws + 4194304;
  float* statsV = ws + 4358144;
  float* w2qg   = ws + 4521984;
  float* b2qg   = ws + 4530176;
  float* slotsS = ws + 4530240;
  float* sposS  = ws + 4534336;
  float* sscaleS= ws + 4534464;
  float* moments= ws + 4534592;             // contiguous with Hsum: 8512
  float* Hsum   = ws + 4534912;
  bf16_t* W1kT  = (bf16_t*)(ws + 4543104);
  bf16_t* W1vT  = (bf16_t*)(ws + 4547200);
  bf16_t* WkT   = (bf16_t*)(ws + 4551296);
  bf16_t* WvT   = (bf16_t*)(ws + 4553344);
  float4* nckA  = (float4*)(ws + 4555392);
  float* nckB   = ws + 4555904;
  float4* ncvA  = (float4*)(ws + 4556032);
  float* ncvB   = ws + 4556544;
  float* possum = ws + 4556672;             // 9
  unsigned* ctr = (unsigned*)(ws + 4556688); // 8

  float* out = (float*)d_out;
  float* outSlots  = out;
  float* outSpos   = out + 4096;
  float* outSscale = out + 4224;
  float* outAttn   = out + 4352;

  k_setup<<<1, 256, 0, stream>>>(in[1], in[2], in[3], in[20], in[21],
                                 in[16], in[17], in[18], in[19], in[4], in[5],
                                 in[8], in[10], slotsS, sposS, sscaleS, moments,
                                 W1kT, W1vT, WkT, WvT, nckA, nckB, ncvA, ncvB,
                                 possum, ctr);
  k_pre<<<512, 256, 0, stream>>>(in[0], in[12], in[13], in[9], in[11],
                                 WkT, WvT, W1kT, W1vT, in[4], in[5],
                                 P0k, P0v, statsK, statsV,
                                 slotsS, in[14], in[15], in[6], in[7], in[22], in[23],
                                 w2qg, b2qg);
  for (int i = 0; i < 4; ++i) {
    if (i < 3) {
      k_iter<0><<<dim3(64, 8), 256, 0, stream>>>(
          P0k, P0v, statsK, statsV, nckA, nckB, ncvA, ncvB, possum,
          w2qg, b2qg, sposS, sscaleS, moments, Hsum, outAttn,
          in[22], in[23], in[24], in[25], in[26], in[27], in[28], in[29],
          in[30], in[31], in[32], in[33], in[14], in[15], in[6], in[7],
          slotsS, outSlots, outSpos, outSscale, ctr);
    } else {
      k_iter<1><<<dim3(64, 8), 256, 0, stream>>>(
          P0k, P0v, statsK, statsV, nckA, nckB, ncvA, ncvB, possum,
          w2qg, b2qg, sposS, sscaleS, moments, Hsum, outAttn,
          in[22], in[23], in[24], in[25], in[26], in[27], in[28], in[29],
          in[30], in[31], in[32], in[33], in[14], in[15], in[6], in[7],
          slotsS, outSlots, outSpos, outSscale, ctr);
    }
  }
}

// Round 6
// 333.145 us; speedup vs baseline: 5.2024x; 5.2024x over previous
//
#include <hip/hip_runtime.h>
#include <math.h>

typedef __bf16 bf16_t;
typedef __bf16 bfrag __attribute__((ext_vector_type(8)));
typedef float ffrag __attribute__((ext_vector_type(4)));

__device__ __forceinline__ float wave_sum(float v) {
#pragma unroll
  for (int m = 32; m >= 1; m >>= 1) v += __shfl_xor(v, m, 64);
  return v;
}
__device__ __forceinline__ float lin_(int i) { return -1.f + (2.f * (float)i) / 63.f; }
__device__ __forceinline__ float bflo(unsigned u) { return __uint_as_float(u << 16); }
__device__ __forceinline__ float bfhi(unsigned u) { return __uint_as_float(u & 0xFFFF0000u); }

// ============ k_pre: weights fold (in-LDS) + LN(inp) -> k0/v0 -> stats+P0 ====
// Also: block 0 performs global setup (state init, nck/ncv fold, possum, ctr);
// consumers are all in later launches, so no intra-launch race.
__device__ __forceinline__ void pass_type(
    const bf16_t xs[][72], bf16_t t0s[][72],
    const bf16_t WTl[][72], const bf16_t W1l[][72],
    const float* __restrict__ bias, const float* wpxs, const float* wpys,
    const float* bpvs, float* __restrict__ statsG, bf16_t* __restrict__ P0G,
    int j0, int wv, int lq, int ln15) {
  ffrag C[4] = {{0,0,0,0},{0,0,0,0},{0,0,0,0},{0,0,0,0}};
#pragma unroll
  for (int ks = 0; ks < 2; ++ks) {
    bfrag a = *(const bfrag*)&xs[wv * 16 + ln15][ks * 32 + lq * 8];
#pragma unroll
    for (int nt = 0; nt < 4; ++nt) {
      bfrag bb = *(const bfrag*)&WTl[nt * 16 + ln15][ks * 32 + lq * 8];
      C[nt] = __builtin_amdgcn_mfma_f32_16x16x32_bf16(a, bb, C[nt], 0, 0, 0);
    }
  }
  float kv[4][4];
  float st[5][4];
#pragma unroll
  for (int i = 0; i < 5; ++i)
#pragma unroll
    for (int rg = 0; rg < 4; ++rg) st[i][rg] = 0.f;
#pragma unroll
  for (int nt = 0; nt < 4; ++nt) {
    int n = nt * 16 + ln15;
    float bn = bias[n], pxw = wpxs[n], pyw = wpys[n], bpw = bpvs[n];
#pragma unroll
    for (int rg = 0; rg < 4; ++rg) {
      float v = C[nt][rg] + bn;
      kv[nt][rg] = v;
      st[0][rg] += v; st[1][rg] += v * v; st[2][rg] += v * pxw;
      st[3][rg] += v * pyw; st[4][rg] += v * bpw;
    }
  }
#pragma unroll
  for (int i = 0; i < 5; ++i)
#pragma unroll
    for (int rg = 0; rg < 4; ++rg) {
      float v = st[i][rg];
      v += __shfl_xor(v, 1, 64); v += __shfl_xor(v, 2, 64);
      v += __shfl_xor(v, 4, 64); v += __shfl_xor(v, 8, 64);
      st[i][rg] = v;
    }
  if (ln15 == 0) {
#pragma unroll
    for (int rg = 0; rg < 4; ++rg) {
      int j = j0 + wv * 16 + lq * 4 + rg;
#pragma unroll
      for (int i = 0; i < 5; ++i) statsG[j * 5 + i] = st[i][rg];
    }
  }
#pragma unroll
  for (int nt = 0; nt < 4; ++nt)
#pragma unroll
    for (int rg = 0; rg < 4; ++rg)
      t0s[wv * 16 + lq * 4 + rg][nt * 16 + ln15] = (bf16_t)kv[nt][rg];
  ffrag D[8] = {{0,0,0,0},{0,0,0,0},{0,0,0,0},{0,0,0,0},
                {0,0,0,0},{0,0,0,0},{0,0,0,0},{0,0,0,0}};
#pragma unroll
  for (int ks = 0; ks < 2; ++ks) {
    bfrag a = *(const bfrag*)&t0s[wv * 16 + ln15][ks * 32 + lq * 8];
#pragma unroll
    for (int nt = 0; nt < 8; ++nt) {
      bfrag bb = *(const bfrag*)&W1l[nt * 16 + ln15][ks * 32 + lq * 8];
      D[nt] = __builtin_amdgcn_mfma_f32_16x16x32_bf16(a, bb, D[nt], 0, 0, 0);
    }
  }
#pragma unroll
  for (int nt = 0; nt < 8; ++nt)
#pragma unroll
    for (int rg = 0; rg < 4; ++rg)
      P0G[(size_t)(j0 + wv * 16 + lq * 4 + rg) * 128 + nt * 16 + ln15] =
          (bf16_t)D[nt][rg];
}

__global__ __launch_bounds__(256) void k_pre(
    const float* __restrict__ inp, const float* __restrict__ g_in,
    const float* __restrict__ b_in, const float* __restrict__ bk,
    const float* __restrict__ bv, const float* __restrict__ Wk,
    const float* __restrict__ Wv, const float* __restrict__ W1,
    const float* __restrict__ b1, const float* __restrict__ g_k,
    const float* __restrict__ b_k, const float* __restrict__ g_v,
    const float* __restrict__ b_v, const float* __restrict__ W_pos,
    const float* __restrict__ b_pos, const float* __restrict__ slots_p,
    const float* __restrict__ s_pos_p, const float* __restrict__ s_scale_p,
    const float* __restrict__ g_slots, const float* __restrict__ b_slots,
    const float* __restrict__ Wq, const float* __restrict__ bq,
    const float* __restrict__ W2, const float* __restrict__ b2,
    bf16_t* __restrict__ P0k, bf16_t* __restrict__ P0v,
    float* __restrict__ statsK, float* __restrict__ statsV,
    float* __restrict__ w2qg, float* __restrict__ b2qg,
    float* __restrict__ slotsS, float* __restrict__ sposS,
    float* __restrict__ sscaleS, float* __restrict__ momentsHsum,
    float4* __restrict__ nckA, float* __restrict__ nckB,
    float4* __restrict__ ncvA, float* __restrict__ ncvB,
    float* __restrict__ possum, unsigned* __restrict__ ctr) {
  __shared__ bf16_t xs[64][72];
  __shared__ bf16_t t0s[64][72];
  __shared__ bf16_t WkTl[64][72];
  __shared__ bf16_t WvTl[64][72];
  __shared__ bf16_t W1kl[128][72];
  __shared__ bf16_t W1vl[128][72];
  __shared__ float wpxs[64], wpys[64], bpvs[64];
  const int tid = threadIdx.x;
  const int j0 = blockIdx.x * 64;
  // fold weights into LDS (reads L2-resident after block 0)
  for (int i = tid; i < 4096; i += 256) {
    int n = i >> 6, d = i & 63;
    WkTl[n][d] = (bf16_t)Wk[d * 64 + n];
    WvTl[n][d] = (bf16_t)Wv[d * 64 + n];
  }
  for (int i = tid; i < 8192; i += 256) {
    int n = i >> 6, c = i & 63;
    float w = W1[c * 128 + n];
    W1kl[n][c] = (bf16_t)(g_k[c] * w);
    W1vl[n][c] = (bf16_t)(g_v[c] * w);
  }
  if (tid < 64) { wpxs[tid] = W_pos[tid]; wpys[tid] = W_pos[64 + tid]; bpvs[tid] = b_pos[tid]; }
  {
    const int px = tid >> 2, cg = tid & 3;
    const float* rowp = inp + (size_t)(j0 + px) * 64 + cg * 16;
    float v[16];
    *(float4*)&v[0]  = ((const float4*)rowp)[0];
    *(float4*)&v[4]  = ((const float4*)rowp)[1];
    *(float4*)&v[8]  = ((const float4*)rowp)[2];
    *(float4*)&v[12] = ((const float4*)rowp)[3];
    float s = 0.f, s2 = 0.f;
#pragma unroll
    for (int i = 0; i < 16; ++i) { s += v[i]; s2 += v[i] * v[i]; }
    s += __shfl_xor(s, 1, 64); s += __shfl_xor(s, 2, 64);
    s2 += __shfl_xor(s2, 1, 64); s2 += __shfl_xor(s2, 2, 64);
    float m = s * 0.015625f;
    float r = rsqrtf(s2 * 0.015625f - m * m + 1e-5f);
    float g[16], bb[16];
    *(float4*)&g[0]  = ((const float4*)(g_in + cg * 16))[0];
    *(float4*)&g[4]  = ((const float4*)(g_in + cg * 16))[1];
    *(float4*)&g[8]  = ((const float4*)(g_in + cg * 16))[2];
    *(float4*)&g[12] = ((const float4*)(g_in + cg * 16))[3];
    *(float4*)&bb[0]  = ((const float4*)(b_in + cg * 16))[0];
    *(float4*)&bb[4]  = ((const float4*)(b_in + cg * 16))[1];
    *(float4*)&bb[8]  = ((const float4*)(b_in + cg * 16))[2];
    *(float4*)&bb[12] = ((const float4*)(b_in + cg * 16))[3];
#pragma unroll
    for (int e = 0; e < 8; ++e) {
      float x0 = (v[2 * e] - m) * r * g[2 * e] + bb[2 * e];
      float x1 = (v[2 * e + 1] - m) * r * g[2 * e + 1] + bb[2 * e + 1];
      union { unsigned u; bf16_t h[2]; } cv;
      cv.h[0] = (bf16_t)x0; cv.h[1] = (bf16_t)x1;
      *(unsigned*)&xs[px][cg * 16 + 2 * e] = cv.u;
    }
  }
  __syncthreads();
  const int wv = tid >> 6, lane = tid & 63, lq = lane >> 4, ln15 = lane & 15;
  pass_type(xs, t0s, WkTl, W1kl, bk, wpxs, wpys, bpvs, statsK, P0k, j0, wv, lq, ln15);
  pass_type(xs, t0s, WvTl, W1vl, bv, wpxs, wpys, bpvs, statsV, P0v, j0, wv, lq, ln15);
  // initial q / w2q / b2q (wave 0 of first 64 blocks), from slots_p directly
  if (blockIdx.x < 64 && tid < 64) {
    int bs = blockIdx.x, d = tid;
    float v = slots_p[(bs & 7) * 64 + d];
    float m = wave_sum(v) * 0.015625f;
    float c = v - m;
    float var = wave_sum(c * c) * 0.015625f;
    float xn = c * rsqrtf(var + 1e-5f) * g_slots[d] + b_slots[d];
    float q = bq[d];
    for (int cc = 0; cc < 64; ++cc) q = fmaf(__shfl(xn, cc, 64), Wq[cc * 64 + d], q);
    float w0 = 0.f, w1 = 0.f;
    for (int cc = 0; cc < 64; ++cc) {
      float qc = __shfl(q, cc, 64);
      w0 = fmaf(W2[d * 64 + cc], qc, w0);
      w1 = fmaf(W2[(64 + d) * 64 + cc], qc, w1);
    }
    w2qg[bs * 128 + d] = w0;
    w2qg[bs * 128 + 64 + d] = w1;
    float p = wave_sum(b2[d] * q);
    if (d == 0) b2qg[bs] = p;
  }
  // block 0: global setup (consumed only by later launches)
  if (blockIdx.x == 0) {
    for (int i = tid; i < 8512; i += 256) momentsHsum[i] = 0.f;
    if (tid < 8) ctr[tid] = 0u;
    for (int i = tid; i < 4096; i += 256) slotsS[i] = slots_p[i & 511];
    if (tid < 128) {
      sposS[tid] = fminf(fmaxf(s_pos_p[tid & 15], -1.f), 1.f);
      sscaleS[tid] = fminf(fmaxf(s_scale_p[tid & 15], 0.001f), 2.f);
    }
    if (tid < 128) {
      int n = tid;
      float wxk = 0, wyk = 0, wbk = 0, uk = 0, sk = 0;
      float wxv = 0, wyv = 0, wbv = 0, uv = 0, sv = 0;
      for (int c = 0; c < 64; ++c) {
        float w = W1[c * 128 + n];
        float wk = g_k[c] * w, wvv = g_v[c] * w;
        float px = W_pos[c], py = W_pos[64 + c], bp = b_pos[c];
        wxk += px * wk; wyk += py * wk; wbk += bp * wk; sk += wk; uk += b_k[c] * w;
        wxv += px * wvv; wyv += py * wvv; wbv += bp * wvv; sv += wvv; uv += b_v[c] * w;
      }
      nckA[n] = make_float4(wxk, wyk, wbk, uk + b1[n]); nckB[n] = sk;
      ncvA[n] = make_float4(wxv, wyv, wbv, uv + b1[n]); ncvB[n] = sv;
    }
    if (tid < 64) {
      float px = W_pos[tid], py = W_pos[64 + tid], bp = b_pos[tid];
      float sarr[9] = {px, py, bp, px * px, py * py, bp * bp, px * py, px * bp, py * bp};
#pragma unroll
      for (int i = 0; i < 9; ++i) {
        float v2 = wave_sum(sarr[i]);
        if (tid == 0) possum[i] = v2;
      }
    }
  }
}

// ============ k_iter: dots -> softmax -> moments -> V-hidden sum =============
// LAST variant also runs a tiny tail finalize (sp/ss + slots copy) via ctr.
template <int LAST>
__global__ __launch_bounds__(256) void k_iter(
    const bf16_t* __restrict__ P0kg, const bf16_t* __restrict__ P0vg,
    const float* __restrict__ statsK, const float* __restrict__ statsV,
    const float4* __restrict__ nckA, const float* __restrict__ nckB,
    const float4* __restrict__ ncvA, const float* __restrict__ ncvB,
    const float* __restrict__ possum, const float* __restrict__ w2qg,
    const float* __restrict__ b2qg, const float* __restrict__ sposS,
    const float* __restrict__ sscaleS, float* __restrict__ moments,
    float* __restrict__ Hsum, float* __restrict__ outAttn,
    const float* __restrict__ slotsS, float* __restrict__ outSlots,
    float* __restrict__ outSpos, float* __restrict__ outSscale,
    unsigned* __restrict__ ctr) {
  __shared__ unsigned Pbuf[64 * 65];
  __shared__ float nck12[64][12];    // per-k' row: A0(4) A1(4) ws0 ws1 pad(2)
  __shared__ float w2q16[64][16];    // per-k' row: q[n even][8s], q[n odd][8s]
  __shared__ float4 scalV[64][9];
  __shared__ float attnS[64][10];
  __shared__ float HsumT[8][128];
  __shared__ float momAcc[8][5];
  __shared__ unsigned s_done;
  const int tid = threadIdx.x;
  const int tile = blockIdx.x, b = blockIdx.y;
  const int jg0 = b * 4096 + tile * 64;
#pragma unroll
  for (int r = 0; r < 4; ++r) {
    int idx = tid + 256 * r;
    int row = idx >> 4, seg = idx & 15;
    uint4 v = ((const uint4*)P0kg)[(size_t)(jg0 + row) * 16 + seg];
    unsigned* dst = &Pbuf[row * 65 + seg * 4];
    dst[0] = v.x; dst[1] = v.y; dst[2] = v.z; dst[3] = v.w;
  }
  if (tid < 128) {
    int n = tid, k = n >> 1, h = n & 1;
    int kp = ((k & 15) << 2) | (k >> 4);
    float4 A = nckA[n];
    *(float4*)&nck12[kp][h * 4] = A;
    nck12[kp][8 + h] = nckB[n];
  }
#pragma unroll
  for (int r = 0; r < 4; ++r) {
    int idx = tid + 256 * r;
    int s = idx >> 7, n = idx & 127;
    int k = n >> 1, h = n & 1;
    int kp = ((k & 15) << 2) | (k >> 4);
    w2q16[kp][h * 8 + s] = w2qg[(b * 8 + s) * 128 + n];
  }
  if (!LAST) {
#pragma unroll
    for (int r = 0; r < 4; ++r) ((float*)HsumT)[tid + 256 * r] = 0.f;
  }
  if (tid < 40) momAcc[tid / 5][tid % 5] = 0.f;
  float4 ncv0 = {0, 0, 0, 0}, ncv1 = {0, 0, 0, 0};
  float wsv0 = 0.f, wsv1 = 0.f;
  if (!LAST) {
    int l = tid & 63;
    ncv0 = ncvA[l]; ncv1 = ncvA[l + 64];
    wsv0 = ncvB[l]; wsv1 = ncvB[l + 64];
  }
  __syncthreads();

  // ---- phase 1: dots for all 8 slots (k-range split over 4 lanes/pixel) ----
  const int px = tid >> 2, sp = tid & 3;
  const int jimg = tile * 64 + px;
  const float gx = lin_(jimg & 63), gy = lin_(jimg >> 6);
  const float Swx = possum[0], Swy = possum[1], Sbp = possum[2];
  const float Swx2 = possum[3], Swy2 = possum[4], Sbp2 = possum[5];
  const float Swxy = possum[6], Swxb = possum[7], Swyb = possum[8];
  float skA[5], svA[5];
#pragma unroll
  for (int i = 0; i < 5; ++i) {
    skA[i] = statsK[(size_t)(jg0 + px) * 5 + i];
    if (!LAST) svA[i] = statsV[(size_t)(jg0 + px) * 5 + i];
  }
  float c1a[8], c2a[8], rKa[8], mrKa[8];
#pragma unroll
  for (int s = 0; s < 8; ++s) {
    int bs = b * 8 + s;
    float spx = sposS[bs * 2], spy = sposS[bs * 2 + 1];
    float rxx = 1.f / (sscaleS[bs * 2] * 5.f);
    float ryy = 1.f / (sscaleS[bs * 2 + 1] * 5.f);
    float c1 = (gx - spx) * rxx, c2 = (gy - spy) * ryy;
    float quad = c1 * c1 * Swx2 + c2 * c2 * Swy2 + Sbp2 +
                 2.f * (c1 * c2 * Swxy + c1 * Swxb + c2 * Swyb);
    float mK = (skA[0] + c1 * Swx + c2 * Swy + Sbp) * 0.015625f;
    float e2K = (skA[1] + 2.f * (c1 * skA[2] + c2 * skA[3] + skA[4]) + quad) * 0.015625f;
    float rK = rsqrtf(e2K - mK * mK + 1e-5f);
    c1a[s] = c1; c2a[s] = c2; rKa[s] = rK; mrKa[s] = mK * rK;
    if (!LAST && (s >> 1) == sp) {
      float mV = (svA[0] + c1 * Swx + c2 * Swy + Sbp) * 0.015625f;
      float e2V = (svA[1] + 2.f * (c1 * svA[2] + c2 * svA[3] + svA[4]) + quad) * 0.015625f;
      float rV = rsqrtf(e2V - mV * mV + 1e-5f);
      scalV[px][s] = make_float4(c1, c2, rV, mV * rV);
    }
  }
  float d8[8] = {0, 0, 0, 0, 0, 0, 0, 0};
#pragma unroll 4
  for (int i = 0; i < 16; ++i) {
    int k = sp * 16 + i;
    unsigned u = Pbuf[px * 65 + k];
    float p0 = bflo(u), p1 = bfhi(u);
    const int kp = (i << 2) | sp;
    const float* nr = &nck12[kp][0];
    float4 A0 = *(const float4*)nr;
    float4 A1 = *(const float4*)(nr + 4);
    float ws0 = nr[8], ws1 = nr[9];
    const float* wr = &w2q16[kp][0];
    float4 q0a = *(const float4*)wr;
    float4 q0b = *(const float4*)(wr + 4);
    float4 q1a = *(const float4*)(wr + 8);
    float4 q1b = *(const float4*)(wr + 12);
    float qq0[8] = {q0a.x, q0a.y, q0a.z, q0a.w, q0b.x, q0b.y, q0b.z, q0b.w};
    float qq1[8] = {q1a.x, q1a.y, q1a.z, q1a.w, q1b.x, q1b.y, q1b.z, q1b.w};
    float bm0 = p0 + A0.z, bm1 = p1 + A1.z;
#pragma unroll
    for (int s = 0; s < 8; ++s) {
      float z0 = bm0 + c1a[s] * A0.x + c2a[s] * A0.y;
      float h0 = fmaxf(fmaf(rKa[s], z0, fmaf(-mrKa[s], ws0, A0.w)), 0.f);
      d8[s] = fmaf(h0, qq0[s], d8[s]);
      float z1 = bm1 + c1a[s] * A1.x + c2a[s] * A1.y;
      float h1 = fmaxf(fmaf(rKa[s], z1, fmaf(-mrKa[s], ws1, A1.w)), 0.f);
      d8[s] = fmaf(h1, qq1[s], d8[s]);
    }
  }
#pragma unroll
  for (int s = 0; s < 8; ++s) {
    float v = d8[s];
    v += __shfl_xor(v, 1, 64);
    v += __shfl_xor(v, 2, 64);
    d8[s] = (v + b2qg[b * 8 + s]) * 0.125f;
  }
  float mx = d8[0];
#pragma unroll
  for (int s = 1; s < 8; ++s) mx = fmaxf(mx, d8[s]);
  float tt = 0.f;
  float e8[8];
#pragma unroll
  for (int s = 0; s < 8; ++s) { e8[s] = expf(d8[s] - mx); tt += e8[s]; }
  float inv = 1.f / tt;
#pragma unroll
  for (int s = 0; s < 8; ++s) e8[s] = e8[s] * inv + 1e-8f;
  float wa, wb;
  if (sp == 0) { wa = e8[0]; wb = e8[1]; }
  else if (sp == 1) { wa = e8[2]; wb = e8[3]; }
  else if (sp == 2) { wa = e8[4]; wb = e8[5]; }
  else { wa = e8[6]; wb = e8[7]; }
  *(float2*)&attnS[px][sp * 2] = make_float2(wa, wb);
  if (LAST) {
    outAttn[(size_t)(b * 8 + sp * 2) * 4096 + jimg] = wa;
    outAttn[(size_t)(b * 8 + sp * 2 + 1) * 4096 + jimg] = wb;
  }
  {
    float mm[10] = {wa, wa * gx, wa * gy, wa * gx * gx, wa * gy * gy,
                    wb, wb * gx, wb * gy, wb * gx * gx, wb * gy * gy};
#pragma unroll
    for (int i = 0; i < 10; ++i) {
      float v = mm[i];
      v += __shfl_xor(v, 4, 64); v += __shfl_xor(v, 8, 64);
      v += __shfl_xor(v, 16, 64); v += __shfl_xor(v, 32, 64);
      mm[i] = v;
    }
    if ((tid & 63) < 4) {
#pragma unroll
      for (int i = 0; i < 5; ++i) {
        atomicAdd(&momAcc[sp * 2][i], mm[i]);
        atomicAdd(&momAcc[sp * 2 + 1][i], mm[5 + i]);
      }
    }
  }
  __syncthreads();   // momAcc complete; Pbuf free for restage

  // ---- phase 2: restage Pbuf with P0v; Hsum += attn * relu(V hidden) -------
  if (!LAST) {
#pragma unroll
    for (int r = 0; r < 4; ++r) {
      int idx = tid + 256 * r;
      int row = idx >> 4, seg = idx & 15;
      uint4 v = ((const uint4*)P0vg)[(size_t)(jg0 + row) * 16 + seg];
      unsigned* dst = &Pbuf[row * 65 + seg * 4];
      dst[0] = v.x; dst[1] = v.y; dst[2] = v.z; dst[3] = v.w;
    }
    __syncthreads();
    const int w = tid >> 6, l = tid & 63;
    float hacc[8][2];
#pragma unroll
    for (int s = 0; s < 8; ++s) { hacc[s][0] = 0.f; hacc[s][1] = 0.f; }
    const unsigned short* P16 = (const unsigned short*)Pbuf;
#pragma unroll 2
    for (int i = 0; i < 16; ++i) {
      int j = w * 16 + i;
      float pv0 = __uint_as_float((unsigned)P16[j * 130 + l] << 16);
      float pv1 = __uint_as_float((unsigned)P16[j * 130 + 64 + l] << 16);
      float bm0 = pv0 + ncv0.z, bm1 = pv1 + ncv1.z;
#pragma unroll
      for (int s = 0; s < 8; ++s) {
        float4 sc = scalV[j][s];
        float aw = attnS[j][s];
        float z0 = bm0 + sc.x * ncv0.x + sc.y * ncv0.y;
        float h0 = fmaxf(fmaf(sc.z, z0, fmaf(-sc.w, wsv0, ncv0.w)), 0.f);
        hacc[s][0] = fmaf(aw, h0, hacc[s][0]);
        float z1 = bm1 + sc.x * ncv1.x + sc.y * ncv1.y;
        float h1 = fmaxf(fmaf(sc.z, z1, fmaf(-sc.w, wsv1, ncv1.w)), 0.f);
        hacc[s][1] = fmaf(aw, h1, hacc[s][1]);
      }
    }
#pragma unroll
    for (int s = 0; s < 8; ++s) {
      atomicAdd(&HsumT[s][l], hacc[s][0]);
      atomicAdd(&HsumT[s][l + 64], hacc[s][1]);
    }
    __syncthreads();
#pragma unroll
    for (int r = 0; r < 4; ++r) {
      int i2 = tid + 256 * r;
      int s = i2 >> 7, n = i2 & 127;
      atomicAdd(&Hsum[(b * 8 + s) * 128 + n], HsumT[s][n]);
    }
  }
  if (tid < 40)
    atomicAdd(&moments[(b * 8 + tid / 5) * 5 + tid % 5], momAcc[tid / 5][tid % 5]);

  // ---- LAST only: tiny tail finalize (sp/ss + outputs), via ctr ------------
  if (LAST) {
    __syncthreads();   // barrier drains global atomics (vmcnt) for all threads
    __threadfence();
    if (tid == 0) s_done = atomicAdd(&ctr[b], 1u);
    __syncthreads();
    if (s_done != 63) return;
    __threadfence();
    if (tid < 40)
      momAcc[tid / 5][tid % 5] = atomicAdd(&moments[(b * 8 + tid / 5) * 5 + tid % 5], 0.f);
    __syncthreads();
    if (tid < 8) {
      int s = tid, bs = b * 8 + s;
      float M0 = momAcc[s][0], M1x = momAcc[s][1], M1y = momAcc[s][2];
      float M2x = momAcc[s][3], M2y = momAcc[s][4];
      float invM0 = 1.f / M0;
      float spx2 = M1x * invM0, spy2 = M1y * invM0;
      float M0a = M0 + 4096.f * 1e-8f;
      float G2 = 1408.6772487f * 1e-8f;
      float vx = (M2x + G2 - 2.f * spx2 * M1x + spx2 * spx2 * M0a) / M0a;
      float vy = (M2y + G2 - 2.f * spy2 * M1y + spy2 * spy2 * M0a) / M0a;
      float ssx = fminf(fmaxf(sqrtf(fmaxf(vx, 0.f)), 0.001f), 2.f);
      float ssy = fminf(fmaxf(sqrtf(fmaxf(vy, 0.f)), 0.001f), 2.f);
      outSpos[bs * 2] = spx2; outSpos[bs * 2 + 1] = spy2;
      outSscale[bs * 2] = ssx; outSscale[bs * 2 + 1] = ssy;
    }
    for (int i = tid; i < 512; i += 256)
      outSlots[b * 512 + i] = slotsS[b * 512 + i];
  }
}

// ============ k_fin: sp/ss, GRU + FFN, next-iter q (verified r3 code) ========
__global__ __launch_bounds__(192) void k_fin(
    float* __restrict__ moments, float* __restrict__ Hsum,
    const float* __restrict__ W2, const float* __restrict__ b2,
    const float* __restrict__ W_ih, const float* __restrict__ b_ih,
    const float* __restrict__ W_hh, const float* __restrict__ b_hh,
    const float* __restrict__ g_pre, const float* __restrict__ b_pre,
    const float* __restrict__ Wf1, const float* __restrict__ bf1,
    const float* __restrict__ Wf2, const float* __restrict__ bf2,
    const float* __restrict__ g_slots, const float* __restrict__ b_slots,
    const float* __restrict__ Wq, const float* __restrict__ bq,
    float* __restrict__ slotsS, float* __restrict__ sposS, float* __restrict__ sscaleS,
    float* __restrict__ w2qg, float* __restrict__ b2qg) {
  const int bs = blockIdx.x;
  const int t = threadIdx.x;
  __shared__ float hsum_s[128], upd[64], sprev[64], xg[192], hg[192];
  __shared__ float snew[64], xpre[64], hf[128], sfin[64], xn[64], qsh[64];
  const float M0 = moments[bs * 5 + 0];
  const float M1x = moments[bs * 5 + 1], M1y = moments[bs * 5 + 2];
  const float M2x = moments[bs * 5 + 3], M2y = moments[bs * 5 + 4];
  const float invM0 = 1.f / M0;
  const float spx = M1x * invM0, spy = M1y * invM0;
  const float M0a = M0 + 4096.f * 1e-8f;
  const float G2 = 1408.6772487f * 1e-8f;
  const float vx = (M2x + G2 - 2.f * spx * M1x + spx * spx * M0a) / M0a;
  const float vy = (M2y + G2 - 2.f * spy * M1y + spy * spy * M0a) / M0a;
  float ssx = fminf(fmaxf(sqrtf(fmaxf(vx, 0.f)), 0.001f), 2.f);
  float ssy = fminf(fmaxf(sqrtf(fmaxf(vy, 0.f)), 0.001f), 2.f);
  if (t == 0) {
    sposS[bs * 2 + 0] = spx; sposS[bs * 2 + 1] = spy;
    sscaleS[bs * 2 + 0] = ssx; sscaleS[bs * 2 + 1] = ssy;
  }
  if (t < 128) hsum_s[t] = Hsum[bs * 128 + t];
  if (t < 64) sprev[t] = slotsS[bs * 64 + t];
  __syncthreads();
  if (t < 128) Hsum[bs * 128 + t] = 0.f;
  if (t < 5) moments[bs * 5 + t] = 0.f;
  if (t < 64) {
    float a = 0.f;
#pragma unroll
    for (int k = 0; k < 128; ++k) a += hsum_s[k] * W2[k * 64 + t];
    upd[t] = a * invM0 + b2[t];
  }
  __syncthreads();
  {
    float a = b_ih[t], h = b_hh[t];
#pragma unroll
    for (int d = 0; d < 64; ++d) {
      a += upd[d] * W_ih[d * 192 + t];
      h += sprev[d] * W_hh[d * 192 + t];
    }
    xg[t] = a; hg[t] = h;
  }
  __syncthreads();
  if (t < 64) {
    float r = 1.f / (1.f + expf(-(xg[t] + hg[t])));
    float z = 1.f / (1.f + expf(-(xg[64 + t] + hg[64 + t])));
    float n = tanhf(xg[128 + t] + r * hg[128 + t]);
    snew[t] = (1.f - z) * n + z * sprev[t];
  }
  __syncthreads();
  if (t < 64) {
    float v = snew[t];
    float m = wave_sum(v) * 0.015625f;
    float c = v - m;
    float var = wave_sum(c * c) * 0.015625f;
    xpre[t] = c * rsqrtf(var + 1e-5f) * g_pre[t] + b_pre[t];
  }
  __syncthreads();
  if (t < 128) {
    float a = bf1[t];
#pragma unroll
    for (int d = 0; d < 64; ++d) a += xpre[d] * Wf1[d * 128 + t];
    hf[t] = fmaxf(a, 0.f);
  }
  __syncthreads();
  if (t < 64) {
    float a = bf2[t];
#pragma unroll
    for (int k = 0; k < 128; ++k) a += hf[k] * Wf2[k * 64 + t];
    float nv = snew[t] + a;
    slotsS[bs * 64 + t] = nv;
    sfin[t] = nv;
  }
  __syncthreads();
  if (t < 64) {
    float v = sfin[t];
    float m = wave_sum(v) * 0.015625f;
    float c = v - m;
    float var = wave_sum(c * c) * 0.015625f;
    xn[t] = c * rsqrtf(var + 1e-5f) * g_slots[t] + b_slots[t];
  }
  __syncthreads();
  if (t < 64) {
    float a = bq[t];
#pragma unroll
    for (int d = 0; d < 64; ++d) a += xn[d] * Wq[d * 64 + t];
    qsh[t] = a;
  }
  __syncthreads();
  if (t < 128) {
    float a = 0.f;
#pragma unroll
    for (int d = 0; d < 64; ++d) a += W2[t * 64 + d] * qsh[d];
    w2qg[bs * 128 + t] = a;
  }
  if (t < 64) {
    float p = wave_sum(b2[t] * qsh[t]);
    if (t == 0) b2qg[bs] = p;
  }
}

extern "C" void kernel_launch(void* const* d_in, const int* in_sizes, int n_in,
                              void* d_out, int out_size, void* d_ws, size_t ws_size,
                              hipStream_t stream) {
  const float* const* in = (const float* const*)d_in;
  float* ws = (float*)d_ws;
  bf16_t* P0k   = (bf16_t*)(ws + 0);
  bf16_t* P0v   = (bf16_t*)(ws + 2097152);
  float* statsK = ws + 4194304;
  float* statsV = ws + 4358144;
  float* w2qg   = ws + 4521984;
  float* b2qg   = ws + 4530176;
  float* slotsS = ws + 4530240;
  float* sposS  = ws + 4534336;
  float* sscaleS= ws + 4534464;
  float* moments= ws + 4534592;             // contiguous with Hsum: 8512
  float* Hsum   = ws + 4534912;
  float4* nckA  = (float4*)(ws + 4543104);
  float* nckB   = ws + 4543616;
  float4* ncvA  = (float4*)(ws + 4543744);
  float* ncvB   = ws + 4544256;
  float* possum = ws + 4544384;             // 9
  unsigned* ctr = (unsigned*)(ws + 4544400); // 8

  float* out = (float*)d_out;
  float* outSlots  = out;
  float* outSpos   = out + 4096;
  float* outSscale = out + 4224;
  float* outAttn   = out + 4352;

  k_pre<<<512, 256, 0, stream>>>(
      in[0], in[12], in[13], in[9], in[11], in[8], in[10], in[20], in[21],
      in[16], in[17], in[18], in[19], in[4], in[5], in[1], in[2], in[3],
      in[14], in[15], in[6], in[7], in[22], in[23],
      P0k, P0v, statsK, statsV, w2qg, b2qg,
      slotsS, sposS, sscaleS, moments, nckA, nckB, ncvA, ncvB, possum, ctr);
  for (int i = 0; i < 3; ++i) {
    k_iter<0><<<dim3(64, 8), 256, 0, stream>>>(
        P0k, P0v, statsK, statsV, nckA, nckB, ncvA, ncvB, possum,
        w2qg, b2qg, sposS, sscaleS, moments, Hsum, outAttn,
        slotsS, outSlots, outSpos, outSscale, ctr);
    k_fin<<<64, 192, 0, stream>>>(moments, Hsum, in[22], in[23], in[24], in[25],
                                  in[26], in[27], in[28], in[29], in[30], in[31],
                                  in[32], in[33], in[14], in[15], in[6], in[7],
                                  slotsS, sposS, sscaleS, w2qg, b2qg);
  }
  k_iter<1><<<dim3(64, 8), 256, 0, stream>>>(
      P0k, P0v, statsK, statsV, nckA, nckB, ncvA, ncvB, possum,
      w2qg, b2qg, sposS, sscaleS, moments, Hsum, outAttn,
      slotsS, outSlots, outSpos, outSscale, ctr);
}